// Round 1
// baseline (497.098 us; speedup 1.0000x reference)
//
#include <hip/hip_runtime.h>

#define N 64
#define NC 128
#define NB 8
#define LSEQ 4096
#define QC 128
#define NCHUNK (LSEQ/QC)   // 32

// workspace layout (float offsets)
#define OFF_ABAR 0                         // [64][64]
#define OFF_AQ   (OFF_ABAR + N*N)          // [64][64]  A_bar^128
#define OFF_BBAR (OFF_AQ + N*N)            // [n][c] 64x128
#define OFF_K    (OFF_BBAR + N*NC)         // k[c][p]  128x128
#define OFF_W    (OFF_K + NC*QC)           // W[p][c][n] 128x128x64
#define OFF_U    (OFF_W + QC*NC*N)         // U[c][n][q] 128x64x128
#define OFF_FS   (OFF_U + NC*N*QC)         // FS[j][b][c][n] 32x8x128x64

__device__ __forceinline__ float rdlane(float v, int l) {
    return __int_as_float(__builtin_amdgcn_readlane(__float_as_int(v), l));
}

// ---------------------------------------------------------------------------
// prep: M = I - dt/2 A ; invM via Gauss-Jordan (A lower-tri, no pivot needed)
//       A_bar = invM (I + dt/2 A) ; B_bar = dt invM B ; AQ = A_bar^128
// ---------------------------------------------------------------------------
__global__ __launch_bounds__(256) void prep_kernel(const float* __restrict__ A,
    const float* __restrict__ B, const float* __restrict__ dtp,
    float* __restrict__ ws)
{
    __shared__ float G[64][130];   // [M | I] augmented
    __shared__ float T1[64*65];
    __shared__ float T2[64*65];
    __shared__ float fcol[64];
    const int tid = threadIdx.x;
    const float dt = dtp[0];
    const float hdt = 0.5f * dt;

    for (int idx = tid; idx < 64*64; idx += 256) {
        int i = idx >> 6, j = idx & 63;
        float a = A[idx];
        G[i][j]    = (i == j ? 1.0f : 0.0f) - hdt * a;
        G[i][64+j] = (i == j ? 1.0f : 0.0f);
    }
    __syncthreads();

    for (int k = 0; k < 64; ++k) {
        if (tid < 64) fcol[tid] = G[tid][k];
        __syncthreads();
        float rpiv = 1.0f / fcol[k];
        if (tid < 128) G[k][tid] *= rpiv;
        __syncthreads();
        for (int idx = tid; idx < 64*128; idx += 256) {
            int i = idx >> 7, j = idx & 127;
            if (i != k) G[i][j] -= fcol[i] * G[k][j];
        }
        __syncthreads();
    }
    // A_bar = invM + hdt * invM @ A   (write T1 + ws)
    for (int idx = tid; idx < 64*64; idx += 256) {
        int i = idx >> 6, j = idx & 63;
        float acc = 0.0f;
        for (int m = 0; m < 64; ++m) acc += G[i][64+m] * A[m*64 + j];
        float ab = G[i][64+j] + hdt * acc;
        T1[i*65 + j] = ab;
        ws[OFF_ABAR + idx] = ab;
    }
    // B_bar = dt * invM @ B
    for (int idx = tid; idx < 64*128; idx += 256) {
        int i = idx >> 7, cc = idx & 127;
        float acc = 0.0f;
        for (int m = 0; m < 64; ++m) acc += G[i][64+m] * B[m*128 + cc];
        ws[OFF_BBAR + idx] = dt * acc;
    }
    __syncthreads();
    // AQ = A_bar^128 (7 squarings)
    float* cur = T1; float* nxt = T2;
    for (int itq = 0; itq < 7; ++itq) {
        for (int idx = tid; idx < 64*64; idx += 256) {
            int i = idx >> 6, j = idx & 63;
            float acc = 0.0f;
            for (int m = 0; m < 64; ++m) acc += cur[i*65 + m] * cur[m*65 + j];
            nxt[i*65 + j] = acc;
        }
        __syncthreads();
        float* t = cur; cur = nxt; nxt = t;
    }
    for (int idx = tid; idx < 64*64; idx += 256) {
        int i = idx >> 6, j = idx & 63;
        ws[OFF_AQ + idx] = cur[i*65 + j];
    }
}

// ---------------------------------------------------------------------------
// powers: per channel c: W[p][c][:] = A_bar^p B_bar[:,c] (p=0..127),
//         k[c][p] = C_c . W[p], U[c][n][q] = ((A^T)^{q+1} C_c)[n]
// wave0 does the W/k chain, wave1 the U chain (independent).
// ---------------------------------------------------------------------------
__global__ __launch_bounds__(128) void powers_kernel(const float* __restrict__ C,
    float* __restrict__ ws)
{
    __shared__ float A_lds[64*65];
    __shared__ float w_lds[64];
    __shared__ float u_lds[64];
    const int tid = threadIdx.x;
    const int c = blockIdx.x;
    for (int idx = tid; idx < 64*64; idx += 128) {
        int i = idx >> 6, m = idx & 63;
        A_lds[i*65 + m] = ws[OFF_ABAR + idx];
    }
    __syncthreads();
    if (tid < 64) {
        int n = tid;
        float w  = ws[OFF_BBAR + n*NC + c];
        float Cn = C[n*NC + c];
        for (int p = 0; p < QC; ++p) {
            ws[OFF_W + (p*NC + c)*N + n] = w;
            float t = Cn * w;
            for (int off = 32; off > 0; off >>= 1) t += __shfl_xor(t, off, 64);
            if (n == 0) ws[OFF_K + c*QC + p] = t;
            w_lds[n] = w;
            float acc = 0.0f;
            for (int m = 0; m < 64; ++m) acc += A_lds[n*65 + m] * w_lds[m];
            w = acc;
        }
    } else {
        int m = tid - 64;
        float u = C[m*NC + c];
        for (int q = 0; q < QC; ++q) {
            u_lds[m] = u;
            float acc = 0.0f;
            for (int nn = 0; nn < 64; ++nn) acc += A_lds[nn*65 + m] * u_lds[nn];
            u = acc;
            ws[OFF_U + (c*N + m)*QC + q] = u;
        }
    }
}

// ---------------------------------------------------------------------------
// fchunk: F[j][b][c][n] = sum_q W[127-q][c][n] * x[b][c][j*128+q]
// block: 4 channels (one per wave), all 8 batches, LDS-tiled over q.
// ---------------------------------------------------------------------------
__global__ __launch_bounds__(256) void fchunk_kernel(const float* __restrict__ x,
    float* __restrict__ ws)
{
    __shared__ float Wt[32*4*64];   // [qq][cw][n]
    __shared__ float xt[8*4*32];    // [b][cw][qq]
    const int tid = threadIdx.x;
    const int cw = tid >> 6;
    const int n = tid & 63;
    const int c0 = blockIdx.x * 4;
    const int j = blockIdx.y;
    float acc[8];
#pragma unroll
    for (int b = 0; b < 8; ++b) acc[b] = 0.0f;
    for (int qt = 0; qt < 4; ++qt) {
        __syncthreads();
        for (int idx = tid; idx < 32*4*64; idx += 256) {
            int qq = idx >> 8; int rem = idx & 255; int cc = rem >> 6; int nn = rem & 63;
            int q = qt*32 + qq;
            Wt[idx] = ws[OFF_W + ((QC-1-q)*NC + c0 + cc)*N + nn];
        }
        for (int idx = tid; idx < 8*4*32; idx += 256) {
            int b = idx >> 7; int rem = idx & 127; int cc = rem >> 5; int qq = rem & 31;
            xt[idx] = x[((b*NC) + c0 + cc)*LSEQ + j*QC + qt*32 + qq];
        }
        __syncthreads();
        for (int qq = 0; qq < 32; ++qq) {
            float wv = Wt[(qq*4 + cw)*64 + n];
#pragma unroll
            for (int b = 0; b < 8; ++b)
                acc[b] += wv * xt[(b*4 + cw)*32 + qq];
        }
    }
    const int c = c0 + cw;
#pragma unroll
    for (int b = 0; b < 8; ++b)
        ws[OFF_FS + ((j*NB + b)*NC + c)*N + n] = acc[b];
}

// ---------------------------------------------------------------------------
// scan: per (b,c) chain over 32 chunks: S_{j+1} = AQ S_j + F_j, in-place.
// slot j ends holding S_{j+1}; chunk j reads slot j-1.
// ---------------------------------------------------------------------------
__global__ __launch_bounds__(64) void scan_kernel(float* __restrict__ ws)
{
    __shared__ float AQ[64*65];
    __shared__ float s_lds[64];
    const int n = threadIdx.x;
    const int b = blockIdx.x >> 7;
    const int c = blockIdx.x & 127;
    for (int idx = n; idx < 64*64; idx += 64) {
        int i = idx >> 6, m = idx & 63;
        AQ[i*65 + m] = ws[OFF_AQ + idx];
    }
    float s = ws[OFF_FS + ((0*NB + b)*NC + c)*N + n];   // S_1 = F_0
    for (int j = 1; j <= NCHUNK - 2; ++j) {
        s_lds[n] = s;
        float f = ws[OFF_FS + ((j*NB + b)*NC + c)*N + n];
        float acc = f;
        for (int m = 0; m < 64; ++m) acc += AQ[n*65 + m] * s_lds[m];
        s = acc;
        ws[OFF_FS + ((j*NB + b)*NC + c)*N + n] = s;
    }
}

// ---------------------------------------------------------------------------
// output: y[b,c,j*128+q] = sum_{i<=q} k[c][q-i] x[b,c,j*128+i]
//                        + sum_n U[c][n][q] * S_j[b][n][c]
// block = one (c, j); 128 threads (thread = q); all 8 b amortized in regs.
// ---------------------------------------------------------------------------
__global__ __launch_bounds__(128) void output_kernel(const float* __restrict__ x,
    const float* __restrict__ ws, float* __restrict__ out)
{
    __shared__ float U_lds[64*128];  // [n][q]
    __shared__ float kc_lds[128];
    const int tid = threadIdx.x;
    const int c = blockIdx.x;
    const int j = blockIdx.y;
    const int q = tid;
    const int lane = tid & 63;
    const int wave = tid >> 6;

    for (int idx = tid; idx < 64*128; idx += 128)
        U_lds[idx] = ws[OFF_U + c*(N*QC) + idx];
    kc_lds[tid] = ws[OFF_K + c*QC + tid];
    __syncthreads();

    float xr0[8], xr1[8], sr[8], acc[8];
#pragma unroll
    for (int b = 0; b < 8; ++b) {
        const float* xp = x + ((long)(b*NC + c))*LSEQ + j*QC;
        xr0[b] = xp[lane];
        xr1[b] = xp[64 + lane];
        sr[b] = (j > 0) ? ws[OFF_FS + (((j-1)*NB + b)*NC + c)*N + lane] : 0.0f;
        acc[b] = 0.0f;
    }
    // intra-chunk triangular convolution
    for (int i = 0; i < 64; ++i) {
        float kv = (i <= q) ? kc_lds[(q - i) & 127] : 0.0f;
#pragma unroll
        for (int b = 0; b < 8; ++b)
            acc[b] += kv * rdlane(xr0[b], i);
    }
    if (wave == 1) {
        for (int i = 64; i < 128; ++i) {
            float kv = (i <= q) ? kc_lds[(q - i) & 127] : 0.0f;
#pragma unroll
            for (int b = 0; b < 8; ++b)
                acc[b] += kv * rdlane(xr1[b], i - 64);
        }
    }
    // inter-chunk term
    if (j > 0) {
        for (int nn = 0; nn < 64; ++nn) {
            float uq = U_lds[nn*128 + q];
#pragma unroll
            for (int b = 0; b < 8; ++b)
                acc[b] += uq * rdlane(sr[b], nn);
        }
    }
#pragma unroll
    for (int b = 0; b < 8; ++b)
        out[((long)(b*NC + c))*LSEQ + j*QC + q] = acc[b];
}

extern "C" void kernel_launch(void* const* d_in, const int* in_sizes, int n_in,
                              void* d_out, int out_size, void* d_ws, size_t ws_size,
                              hipStream_t stream)
{
    const float* signal = (const float*)d_in[0];
    const float* B      = (const float*)d_in[1];
    const float* C      = (const float*)d_in[2];
    const float* A      = (const float*)d_in[3];
    const float* dt     = (const float*)d_in[4];
    float* ws  = (float*)d_ws;
    float* out = (float*)d_out;

    hipLaunchKernelGGL(prep_kernel,   dim3(1),        dim3(256), 0, stream, A, B, dt, ws);
    hipLaunchKernelGGL(powers_kernel, dim3(NC),       dim3(128), 0, stream, C, ws);
    hipLaunchKernelGGL(fchunk_kernel, dim3(32, NCHUNK), dim3(256), 0, stream, signal, ws);
    hipLaunchKernelGGL(scan_kernel,   dim3(NB*NC),    dim3(64),  0, stream, ws);
    hipLaunchKernelGGL(output_kernel, dim3(NC, NCHUNK), dim3(128), 0, stream, signal, ws, out);
}

// Round 2
// 191.787 us; speedup vs baseline: 2.5919x; 2.5919x over previous
//
#include <hip/hip_runtime.h>

#define N 64
#define NC 128
#define NB 8
#define LSEQ 4096
#define QC 128
#define NCHUNK (LSEQ/QC)   // 32

// workspace layout (float offsets)
#define OFF_ABAR 0                         // [n][m] 64x64  A_bar row-major
#define OFF_AQ   (OFF_ABAR + N*N)          // [n][m] 64x64  A_bar^128
#define OFF_BBAR (OFF_AQ + N*N)            // [n][c] 64x128
#define OFF_K    (OFF_BBAR + N*NC)         // k[c][p]  128x128
#define OFF_W    (OFF_K + NC*QC)           // W[p][c][n] 128x128x64
#define OFF_U    (OFF_W + QC*NC*N)         // U[c][q][n] 128x128x64
#define OFF_FS   (OFF_U + NC*QC*N)         // FS[j][b][c][n] 32x8x128x64
#define OFF_ABT  OFF_FS                    // [j][l] 64x64 A_bar^T (dead before fchunk writes FS)

__device__ __forceinline__ float rdlane(float v, int l) {
    return __int_as_float(__builtin_amdgcn_readlane(__float_as_int(v), l));
}

// ---------------------------------------------------------------------------
// prep_cols: forward-substitution column solves of (I - h A) x = v.
//   cols 0..63   : A_bar col j  (v = e_j + h A[:,j]),  also writes A_bar^T
//   cols 64..191 : B_bar col c  (v = B[:,c], result * dt)
// One wave per column; A lower-triangular so no pivoting.
// ---------------------------------------------------------------------------
__global__ __launch_bounds__(256) void prep_cols_kernel(const float* __restrict__ A,
    const float* __restrict__ B, const float* __restrict__ dtp,
    float* __restrict__ ws)
{
    __shared__ float AT[64*65];    // AT[i][l] = A[l][i]
    const int tid  = threadIdx.x;
    const int wave = tid >> 6;
    const int l    = tid & 63;
    const float dt = dtp[0];
    const float h  = 0.5f * dt;

    for (int idx = tid; idx < 64*64; idx += 256) {
        int row = idx >> 6, i = idx & 63;          // read A coalesced
        AT[i*65 + row] = A[idx];
    }
    __syncthreads();

    const float rdv = 1.0f / (1.0f - h * AT[l*65 + l]);   // 1/M[l][l]
    const int colid = blockIdx.x * 4 + wave;              // 0..191

    float r;
    if (colid < 64) {
        int j = colid;
        r = ((l == j) ? 1.0f : 0.0f) + h * AT[j*65 + l];  // (I + hA)[:,j]
    } else {
        int c = colid - 64;
        r = B[l*NC + c];
    }

#pragma unroll
    for (int i = 0; i < 64; ++i) {
        float xi = rdlane(r, i) * rdlane(rdv, i);
        float a  = AT[i*65 + l];                  // A[l][i] (0 for l<i)
        r = fmaf(h * xi, a, r);
        r = (l == i) ? xi : r;
    }

    if (colid < 64) {
        ws[OFF_ABAR + l*64 + colid] = r;          // column scatter
        ws[OFF_ABT  + colid*64 + l] = r;          // transposed row, coalesced
    } else {
        ws[OFF_BBAR + l*NC + (colid - 64)] = dt * r;
    }
}

// ---------------------------------------------------------------------------
// chains: 320 one-wave blocks, A-row held in 64 VGPRs, vector broadcast via
// v_readlane (constant lane index, inner loop unrolled).
//   blocks   0..127 : W[p][c][:] = A_bar^p B_bar[:,c], k[c][p] = C_c . W[p]
//   blocks 128..255 : U[c][q][:] = (A_bar^T)^(q+1) C_c
//   blocks 256..319 : AQ col j = A_bar^128 e_j
// ---------------------------------------------------------------------------
__global__ __launch_bounds__(64) void chains_kernel(const float* __restrict__ C,
    float* __restrict__ ws)
{
    const int bid = blockIdx.x;
    const int l   = threadIdx.x;

    float ar[64];
    {
        const float4* rp = (bid < 128 || bid >= 256)
            ? reinterpret_cast<const float4*>(ws + OFF_ABAR + l*64)   // row l of A_bar
            : reinterpret_cast<const float4*>(ws + OFF_ABT  + l*64);  // row l of A_bar^T
#pragma unroll
        for (int t = 0; t < 16; ++t) {
            float4 v = rp[t];
            ar[4*t+0] = v.x; ar[4*t+1] = v.y; ar[4*t+2] = v.z; ar[4*t+3] = v.w;
        }
    }

    if (bid < 128) {                       // ---- W / k chain, channel c
        const int c = bid;
        float w  = ws[OFF_BBAR + l*NC + c];
        float Cn = C[l*NC + c];
        for (int p = 0; p < QC; ++p) {
            ws[OFF_W + (p*NC + c)*N + l] = w;
            float t = Cn * w;
            t += __shfl_xor(t, 32, 64); t += __shfl_xor(t, 16, 64);
            t += __shfl_xor(t, 8, 64);  t += __shfl_xor(t, 4, 64);
            t += __shfl_xor(t, 2, 64);  t += __shfl_xor(t, 1, 64);
            if (l == 0) ws[OFF_K + c*QC + p] = t;
            float a0 = 0.f, a1 = 0.f, a2 = 0.f, a3 = 0.f;
#pragma unroll
            for (int m = 0; m < 64; m += 4) {
                a0 += ar[m+0] * rdlane(w, m+0);
                a1 += ar[m+1] * rdlane(w, m+1);
                a2 += ar[m+2] * rdlane(w, m+2);
                a3 += ar[m+3] * rdlane(w, m+3);
            }
            w = (a0 + a1) + (a2 + a3);
        }
    } else if (bid < 256) {                // ---- U chain, channel c
        const int c = bid - 128;
        float u = C[l*NC + c];
        for (int q = 0; q < QC; ++q) {
            float a0 = 0.f, a1 = 0.f, a2 = 0.f, a3 = 0.f;
#pragma unroll
            for (int m = 0; m < 64; m += 4) {
                a0 += ar[m+0] * rdlane(u, m+0);
                a1 += ar[m+1] * rdlane(u, m+1);
                a2 += ar[m+2] * rdlane(u, m+2);
                a3 += ar[m+3] * rdlane(u, m+3);
            }
            u = (a0 + a1) + (a2 + a3);
            ws[OFF_U + (c*QC + q)*N + l] = u;   // coalesced
        }
    } else {                               // ---- AQ column j
        const int j = bid - 256;
        float w = (l == j) ? 1.0f : 0.0f;
        for (int p = 0; p < QC; ++p) {
            float a0 = 0.f, a1 = 0.f, a2 = 0.f, a3 = 0.f;
#pragma unroll
            for (int m = 0; m < 64; m += 4) {
                a0 += ar[m+0] * rdlane(w, m+0);
                a1 += ar[m+1] * rdlane(w, m+1);
                a2 += ar[m+2] * rdlane(w, m+2);
                a3 += ar[m+3] * rdlane(w, m+3);
            }
            w = (a0 + a1) + (a2 + a3);
        }
        ws[OFF_AQ + l*64 + j] = w;
    }
}

// ---------------------------------------------------------------------------
// fchunk: F[j][b][c][n] = sum_q W[127-q][c][n] * x[b][c][j*128+q]
// 4 waves/block = 4 channels; x held in regs, broadcast via readlane;
// W read coalesced from L2.
// ---------------------------------------------------------------------------
__global__ __launch_bounds__(256) void fchunk_kernel(const float* __restrict__ x,
    float* __restrict__ ws)
{
    const int tid = threadIdx.x;
    const int cw  = tid >> 6;
    const int l   = tid & 63;
    const int c   = blockIdx.x * 4 + cw;
    const int j   = blockIdx.y;

    float xr0[8], xr1[8], acc[8];
#pragma unroll
    for (int b = 0; b < 8; ++b) {
        const float* xp = x + ((long)(b*NC + c))*LSEQ + j*QC;
        xr0[b] = xp[l];
        xr1[b] = xp[64 + l];
        acc[b] = 0.0f;
    }
    const float* wsW = ws + OFF_W;
#pragma unroll 4
    for (int q = 0; q < 64; ++q) {
        float wv = wsW[((QC-1-q)*NC + c)*N + l];
#pragma unroll
        for (int b = 0; b < 8; ++b)
            acc[b] += wv * rdlane(xr0[b], q);
    }
#pragma unroll 4
    for (int q = 64; q < 128; ++q) {
        float wv = wsW[((QC-1-q)*NC + c)*N + l];
#pragma unroll
        for (int b = 0; b < 8; ++b)
            acc[b] += wv * rdlane(xr1[b], q - 64);
    }
#pragma unroll
    for (int b = 0; b < 8; ++b)
        ws[OFF_FS + ((j*NB + b)*NC + c)*N + l] = acc[b];
}

// ---------------------------------------------------------------------------
// scan: per (b,c): S_{j+1} = AQ S_j + F_j over 32 chunks, in-place.
// AQ row in 64 VGPRs, broadcast via readlane. Slot j ends holding S_{j+1}.
// ---------------------------------------------------------------------------
__global__ __launch_bounds__(64) void scan_kernel(float* __restrict__ ws)
{
    const int l = threadIdx.x;
    const int b = blockIdx.x >> 7;
    const int c = blockIdx.x & 127;

    float aq[64];
    {
        const float4* rp = reinterpret_cast<const float4*>(ws + OFF_AQ + l*64);
#pragma unroll
        for (int t = 0; t < 16; ++t) {
            float4 v = rp[t];
            aq[4*t+0] = v.x; aq[4*t+1] = v.y; aq[4*t+2] = v.z; aq[4*t+3] = v.w;
        }
    }
    float s = ws[OFF_FS + ((0*NB + b)*NC + c)*N + l];   // S_1 = F_0
    for (int j = 1; j <= NCHUNK - 2; ++j) {
        float f = ws[OFF_FS + ((j*NB + b)*NC + c)*N + l];
        float a0 = f, a1 = 0.f, a2 = 0.f, a3 = 0.f;
#pragma unroll
        for (int m = 0; m < 64; m += 4) {
            a0 += aq[m+0] * rdlane(s, m+0);
            a1 += aq[m+1] * rdlane(s, m+1);
            a2 += aq[m+2] * rdlane(s, m+2);
            a3 += aq[m+3] * rdlane(s, m+3);
        }
        s = (a0 + a1) + (a2 + a3);
        ws[OFF_FS + ((j*NB + b)*NC + c)*N + l] = s;
    }
}

// ---------------------------------------------------------------------------
// output: y[b,c,j*128+q] = sum_{i<=q} k[c][q-i] x[b,c,j*128+i]
//                        + sum_n U[c][q][n] * S_j[b][n][c]
// block = one (c, j); 128 threads (thread = q); 8 batches in regs.
// ---------------------------------------------------------------------------
__global__ __launch_bounds__(128) void output_kernel(const float* __restrict__ x,
    const float* __restrict__ ws, float* __restrict__ out)
{
    __shared__ float U_lds[128*65];  // [q][n] padded
    __shared__ float kc_lds[128];
    const int tid = threadIdx.x;
    const int c = blockIdx.x;
    const int j = blockIdx.y;
    const int q = tid;
    const int lane = tid & 63;
    const int wave = tid >> 6;

    for (int idx = tid; idx < 128*64; idx += 128) {
        int qq = idx >> 6, nn = idx & 63;
        U_lds[qq*65 + nn] = ws[OFF_U + c*(QC*N) + idx];
    }
    kc_lds[tid] = ws[OFF_K + c*QC + tid];
    __syncthreads();

    float xr0[8], xr1[8], sr[8], acc[8];
#pragma unroll
    for (int b = 0; b < 8; ++b) {
        const float* xp = x + ((long)(b*NC + c))*LSEQ + j*QC;
        xr0[b] = xp[lane];
        xr1[b] = xp[64 + lane];
        sr[b] = (j > 0) ? ws[OFF_FS + (((j-1)*NB + b)*NC + c)*N + lane] : 0.0f;
        acc[b] = 0.0f;
    }
    // intra-chunk triangular convolution
    for (int i = 0; i < 64; ++i) {
        float kv = (i <= q) ? kc_lds[(q - i) & 127] : 0.0f;
#pragma unroll
        for (int b = 0; b < 8; ++b)
            acc[b] += kv * rdlane(xr0[b], i);
    }
    if (wave == 1) {
        for (int i = 64; i < 128; ++i) {
            float kv = (i <= q) ? kc_lds[(q - i) & 127] : 0.0f;
#pragma unroll
            for (int b = 0; b < 8; ++b)
                acc[b] += kv * rdlane(xr1[b], i - 64);
        }
    }
    // inter-chunk term
    if (j > 0) {
        for (int nn = 0; nn < 64; ++nn) {
            float uq = U_lds[q*65 + nn];
#pragma unroll
            for (int b = 0; b < 8; ++b)
                acc[b] += uq * rdlane(sr[b], nn);
        }
    }
#pragma unroll
    for (int b = 0; b < 8; ++b)
        out[((long)(b*NC + c))*LSEQ + j*QC + q] = acc[b];
}

extern "C" void kernel_launch(void* const* d_in, const int* in_sizes, int n_in,
                              void* d_out, int out_size, void* d_ws, size_t ws_size,
                              hipStream_t stream)
{
    const float* signal = (const float*)d_in[0];
    const float* B      = (const float*)d_in[1];
    const float* C      = (const float*)d_in[2];
    const float* A      = (const float*)d_in[3];
    const float* dt     = (const float*)d_in[4];
    float* ws  = (float*)d_ws;
    float* out = (float*)d_out;

    hipLaunchKernelGGL(prep_cols_kernel, dim3(48),          dim3(256), 0, stream, A, B, dt, ws);
    hipLaunchKernelGGL(chains_kernel,    dim3(320),         dim3(64),  0, stream, C, ws);
    hipLaunchKernelGGL(fchunk_kernel,    dim3(32, NCHUNK),  dim3(256), 0, stream, signal, ws);
    hipLaunchKernelGGL(scan_kernel,      dim3(NB*NC),       dim3(64),  0, stream, ws);
    hipLaunchKernelGGL(output_kernel,    dim3(NC, NCHUNK),  dim3(128), 0, stream, signal, ws, out);
}

// Round 3
// 126.592 us; speedup vs baseline: 3.9268x; 1.5150x over previous
//
#include <hip/hip_runtime.h>

#define N 64
#define NC 128
#define NB 8
#define LSEQ 4096
#define QC 128
#define NCHUNK (LSEQ/QC)   // 32

// workspace layout (float offsets)
#define OFF_ABAR 0                         // [n][m] 64x64  A_bar row-major
#define OFF_AQ   (OFF_ABAR + N*N)          // [n][m] 64x64  A_bar^128
#define OFF_BBAR (OFF_AQ + N*N)            // [n][c] 64x128
#define OFF_K    (OFF_BBAR + N*NC)         // k[c][p]  128x128
#define OFF_W    (OFF_K + NC*QC)           // W[p][c][n] 128x128x64
#define OFF_U    (OFF_W + QC*NC*N)         // U[c][q][n] 128x128x64
#define OFF_FS   (OFF_U + NC*QC*N)         // FS[j][b][c][n] 32x8x128x64
#define OFF_ABT  OFF_FS                    // [j][l] 64x64 A_bar^T (dead before fchunk writes FS)

typedef __attribute__((ext_vector_type(8)))  __bf16 bf16x8;
typedef __attribute__((ext_vector_type(16))) float  f32x16;
typedef __attribute__((ext_vector_type(4)))  unsigned int u32x4;

__device__ __forceinline__ float rdlane(float v, int l) {
    return __int_as_float(__builtin_amdgcn_readlane(__float_as_int(v), l));
}

// fp32 -> (hi, lo) bf16 pair, RNE both
__device__ __forceinline__ void f2bf_hl(float x, unsigned short& hi, unsigned short& lo) {
    unsigned u = __float_as_uint(x);
    unsigned r = (u + 0x7fffu + ((u >> 16) & 1u)) >> 16;
    hi = (unsigned short)r;
    float fh = __uint_as_float(r << 16);
    float l  = x - fh;
    unsigned ul = __float_as_uint(l);
    unsigned rl = (ul + 0x7fffu + ((ul >> 16) & 1u)) >> 16;
    lo = (unsigned short)rl;
}

__device__ __forceinline__ bf16x8 ld_frag(const unsigned short* p) {
    u32x4 v = *(const u32x4*)p;     // 16B-aligned by construction
    return __builtin_bit_cast(bf16x8, v);
}

__device__ __forceinline__ bf16x8 pack8(const unsigned short* v) {
    u32x4 u;
    u.x = v[0] | ((unsigned)v[1] << 16);
    u.y = v[2] | ((unsigned)v[3] << 16);
    u.z = v[4] | ((unsigned)v[5] << 16);
    u.w = v[6] | ((unsigned)v[7] << 16);
    return __builtin_bit_cast(bf16x8, u);
}

// ---------------------------------------------------------------------------
// prep_cols: forward-substitution column solves of (I - h A) x = v.
// ---------------------------------------------------------------------------
__global__ __launch_bounds__(256) void prep_cols_kernel(const float* __restrict__ A,
    const float* __restrict__ B, const float* __restrict__ dtp,
    float* __restrict__ ws)
{
    __shared__ float AT[64*65];    // AT[i][l] = A[l][i]
    const int tid  = threadIdx.x;
    const int wave = tid >> 6;
    const int l    = tid & 63;
    const float dt = dtp[0];
    const float h  = 0.5f * dt;

    for (int idx = tid; idx < 64*64; idx += 256) {
        int row = idx >> 6, i = idx & 63;
        AT[i*65 + row] = A[idx];
    }
    __syncthreads();

    const float rdv = 1.0f / (1.0f - h * AT[l*65 + l]);
    const int colid = blockIdx.x * 4 + wave;

    float r;
    if (colid < 64) {
        int j = colid;
        r = ((l == j) ? 1.0f : 0.0f) + h * AT[j*65 + l];
    } else {
        int c = colid - 64;
        r = B[l*NC + c];
    }

#pragma unroll
    for (int i = 0; i < 64; ++i) {
        float xi = rdlane(r, i) * rdlane(rdv, i);
        float a  = AT[i*65 + l];
        r = fmaf(h * xi, a, r);
        r = (l == i) ? xi : r;
    }

    if (colid < 64) {
        ws[OFF_ABAR + l*64 + colid] = r;
        ws[OFF_ABT  + colid*64 + l] = r;
    } else {
        ws[OFF_BBAR + l*NC + (colid - 64)] = dt * r;
    }
}

// ---------------------------------------------------------------------------
// chains: 320 one-wave blocks, A-row in 64 VGPRs, broadcast via v_readlane.
// ---------------------------------------------------------------------------
__global__ __launch_bounds__(64) void chains_kernel(const float* __restrict__ C,
    float* __restrict__ ws)
{
    const int bid = blockIdx.x;
    const int l   = threadIdx.x;

    float ar[64];
    {
        const float4* rp = (bid < 128 || bid >= 256)
            ? reinterpret_cast<const float4*>(ws + OFF_ABAR + l*64)
            : reinterpret_cast<const float4*>(ws + OFF_ABT  + l*64);
#pragma unroll
        for (int t = 0; t < 16; ++t) {
            float4 v = rp[t];
            ar[4*t+0] = v.x; ar[4*t+1] = v.y; ar[4*t+2] = v.z; ar[4*t+3] = v.w;
        }
    }

    if (bid < 128) {                       // ---- W / k chain, channel c
        const int c = bid;
        float w  = ws[OFF_BBAR + l*NC + c];
        float Cn = C[l*NC + c];
        for (int p = 0; p < QC; ++p) {
            ws[OFF_W + (p*NC + c)*N + l] = w;
            float t = Cn * w;
            t += __shfl_xor(t, 32, 64); t += __shfl_xor(t, 16, 64);
            t += __shfl_xor(t, 8, 64);  t += __shfl_xor(t, 4, 64);
            t += __shfl_xor(t, 2, 64);  t += __shfl_xor(t, 1, 64);
            if (l == 0) ws[OFF_K + c*QC + p] = t;
            float a0 = 0.f, a1 = 0.f, a2 = 0.f, a3 = 0.f;
#pragma unroll
            for (int m = 0; m < 64; m += 4) {
                a0 += ar[m+0] * rdlane(w, m+0);
                a1 += ar[m+1] * rdlane(w, m+1);
                a2 += ar[m+2] * rdlane(w, m+2);
                a3 += ar[m+3] * rdlane(w, m+3);
            }
            w = (a0 + a1) + (a2 + a3);
        }
    } else if (bid < 256) {                // ---- U chain, channel c
        const int c = bid - 128;
        float u = C[l*NC + c];
        for (int q = 0; q < QC; ++q) {
            float a0 = 0.f, a1 = 0.f, a2 = 0.f, a3 = 0.f;
#pragma unroll
            for (int m = 0; m < 64; m += 4) {
                a0 += ar[m+0] * rdlane(u, m+0);
                a1 += ar[m+1] * rdlane(u, m+1);
                a2 += ar[m+2] * rdlane(u, m+2);
                a3 += ar[m+3] * rdlane(u, m+3);
            }
            u = (a0 + a1) + (a2 + a3);
            ws[OFF_U + (c*QC + q)*N + l] = u;
        }
    } else {                               // ---- AQ column j
        const int j = bid - 256;
        float w = (l == j) ? 1.0f : 0.0f;
        for (int p = 0; p < QC; ++p) {
            float a0 = 0.f, a1 = 0.f, a2 = 0.f, a3 = 0.f;
#pragma unroll
            for (int m = 0; m < 64; m += 4) {
                a0 += ar[m+0] * rdlane(w, m+0);
                a1 += ar[m+1] * rdlane(w, m+1);
                a2 += ar[m+2] * rdlane(w, m+2);
                a3 += ar[m+3] * rdlane(w, m+3);
            }
            w = (a0 + a1) + (a2 + a3);
        }
        ws[OFF_AQ + l*64 + j] = w;
    }
}

// ---------------------------------------------------------------------------
// fchunk (MFMA): per channel c, col-group g (64 cols of (j,b)):
//   F[64 n][64 col] = Wrev[64 n][128 kq] @ X[128 kq][64 col], 3-pass bf16 split
// 4 waves = 2 m-tiles x 2 n-tiles of 32x32.
// ---------------------------------------------------------------------------
#define FKP 136   // K-pad (bf16 elems), 272B row stride (16B mult)
__global__ __launch_bounds__(256, 2) void fchunk_mfma_kernel(const float* __restrict__ x,
    float* __restrict__ ws)
{
    __shared__ __align__(16) unsigned short Wh[64*FKP], Wl[64*FKP];
    __shared__ __align__(16) unsigned short Xh[64*FKP], Xl[64*FKP];
    const int tid = threadIdx.x;
    const int c = blockIdx.x;
    const int g = blockIdx.y;

    // stage Wrev: A[n][kq] = W[127-kq][c][n]
    for (int idx = tid; idx < 128*64; idx += 256) {
        int p = idx >> 6, nn = idx & 63;
        float wv = ws[OFF_W + (p*NC + c)*N + nn];
        unsigned short hi, lo; f2bf_hl(wv, hi, lo);
        int kq = 127 - p;
        Wh[nn*FKP + kq] = hi; Wl[nn*FKP + kq] = lo;
    }
    // stage X: B[col][kk] = x[b][c][j*128+kk], col = (j-g*8)*8+b
    for (int idx = tid; idx < 64*128; idx += 256) {
        int col = idx >> 7, kk = idx & 127;
        int j = g*8 + (col >> 3), b = col & 7;
        float xv = x[((long)(b*NC + c))*LSEQ + j*QC + kk];
        unsigned short hi, lo; f2bf_hl(xv, hi, lo);
        Xh[col*FKP + kk] = hi; Xl[col*FKP + kk] = lo;
    }
    __syncthreads();

    const int l = tid & 63;
    const int w = tid >> 6;
    const int lane2 = l & 31;
    const int h = l >> 5;
    const int mt = w & 1;       // m-tile (n-index block)
    const int nt = w >> 1;      // n-tile (col block)

    f32x16 a0 = {}, a1 = {}, a2 = {};
#pragma unroll
    for (int t = 0; t < 8; ++t) {
        bf16x8 ah = ld_frag(&Wh[(mt*32 + lane2)*FKP + 16*t + 8*h]);
        bf16x8 al = ld_frag(&Wl[(mt*32 + lane2)*FKP + 16*t + 8*h]);
        bf16x8 bh = ld_frag(&Xh[(nt*32 + lane2)*FKP + 16*t + 8*h]);
        bf16x8 bl = ld_frag(&Xl[(nt*32 + lane2)*FKP + 16*t + 8*h]);
        a0 = __builtin_amdgcn_mfma_f32_32x32x16_bf16(ah, bh, a0, 0, 0, 0);
        a1 = __builtin_amdgcn_mfma_f32_32x32x16_bf16(al, bh, a1, 0, 0, 0);
        a2 = __builtin_amdgcn_mfma_f32_32x32x16_bf16(ah, bl, a2, 0, 0, 0);
    }
    f32x16 s = a0 + a1 + a2;
    const int col = g*64 + nt*32 + lane2;
    const int j = col >> 3, b = col & 7;
#pragma unroll
    for (int r = 0; r < 16; ++r) {
        int n = mt*32 + (r & 3) + 8*(r >> 2) + 4*h;
        ws[OFF_FS + ((j*NB + b)*NC + c)*N + n] = s[r];
    }
}

// ---------------------------------------------------------------------------
// scan: per (b,c): S_{j+1} = AQ S_j + F_j over 32 chunks, in-place.
// ---------------------------------------------------------------------------
__global__ __launch_bounds__(64) void scan_kernel(float* __restrict__ ws)
{
    const int l = threadIdx.x;
    const int b = blockIdx.x >> 7;
    const int c = blockIdx.x & 127;

    float aq[64];
    {
        const float4* rp = reinterpret_cast<const float4*>(ws + OFF_AQ + l*64);
#pragma unroll
        for (int t = 0; t < 16; ++t) {
            float4 v = rp[t];
            aq[4*t+0] = v.x; aq[4*t+1] = v.y; aq[4*t+2] = v.z; aq[4*t+3] = v.w;
        }
    }
    float s = ws[OFF_FS + ((0*NB + b)*NC + c)*N + l];
    for (int j = 1; j <= NCHUNK - 2; ++j) {
        float f = ws[OFF_FS + ((j*NB + b)*NC + c)*N + l];
        float a0 = f, a1 = 0.f, a2 = 0.f, a3 = 0.f;
#pragma unroll
        for (int m = 0; m < 64; m += 4) {
            a0 += aq[m+0] * rdlane(s, m+0);
            a1 += aq[m+1] * rdlane(s, m+1);
            a2 += aq[m+2] * rdlane(s, m+2);
            a3 += aq[m+3] * rdlane(s, m+3);
        }
        s = (a0 + a1) + (a2 + a3);
        ws[OFF_FS + ((j*NB + b)*NC + c)*N + l] = s;
    }
}

// ---------------------------------------------------------------------------
// output (MFMA): per channel c, col-group g: Y[128 q][64 col] =
//   [T | U](128 x 192) @ [X ; S](192 x 64), 3-pass bf16 split.
// T[q][i]=k[q-i] gathered from reversed-k LDS array (never materialized).
// 4 waves = 4 m-tiles; each wave does both n-tiles.
// ---------------------------------------------------------------------------
#define BKP 200   // B K-pad (192+8), 400B rows
#define UKP 72    // U n-pad (64+8), 144B rows
__global__ __launch_bounds__(256, 1) void output_mfma_kernel(const float* __restrict__ x,
    const float* __restrict__ ws, float* __restrict__ out)
{
    __shared__ __align__(16) unsigned short krh[256], krl[256];
    __shared__ __align__(16) unsigned short Uh[128*UKP], Ul[128*UKP];
    __shared__ __align__(16) unsigned short Bh[64*BKP], Bl[64*BKP];
    const int tid = threadIdx.x;
    const int c = blockIdx.x;
    const int g = blockIdx.y;

    // kr[I] = k_c[127-I] for I<=127 else 0
    {
        int I = tid;
        if (I < 256) {
            float kv = (I < 128) ? ws[OFF_K + c*QC + (127 - I)] : 0.0f;
            unsigned short hi, lo; f2bf_hl(kv, hi, lo);
            krh[I] = hi; krl[I] = lo;
        }
    }
    // U[q][n]
    for (int idx = tid; idx < 128*64; idx += 256) {
        int qq = idx >> 6, nn = idx & 63;
        float uv = ws[OFF_U + (c*QC + qq)*N + nn];
        unsigned short hi, lo; f2bf_hl(uv, hi, lo);
        Uh[qq*UKP + nn] = hi; Ul[qq*UKP + nn] = lo;
    }
    // B rows 0..127: X
    for (int idx = tid; idx < 64*128; idx += 256) {
        int col = idx >> 7, kk = idx & 127;
        int j = g*8 + (col >> 3), b = col & 7;
        float xv = x[((long)(b*NC + c))*LSEQ + j*QC + kk];
        unsigned short hi, lo; f2bf_hl(xv, hi, lo);
        Bh[col*BKP + kk] = hi; Bl[col*BKP + kk] = lo;
    }
    // B rows 128..191: S_j = FS[j-1] (0 for j==0)
    for (int idx = tid; idx < 64*64; idx += 256) {
        int col = idx >> 6, nn = idx & 63;
        int j = g*8 + (col >> 3), b = col & 7;
        float sv = (j > 0) ? ws[OFF_FS + (((j-1)*NB + b)*NC + c)*N + nn] : 0.0f;
        unsigned short hi, lo; f2bf_hl(sv, hi, lo);
        Bh[col*BKP + 128 + nn] = hi; Bl[col*BKP + 128 + nn] = lo;
    }
    __syncthreads();

    const int l = tid & 63;
    const int w = tid >> 6;        // m-tile: rows w*32..w*32+31 (q)
    const int lane2 = l & 31;
    const int h = l >> 5;
    const int m = w*32 + lane2;    // output row q for A-frag

    f32x16 a0[2] = {{}, {}}, a1[2] = {{}, {}}, a2[2] = {{}, {}};

#pragma unroll
    for (int t = 0; t < 12; ++t) {
        bf16x8 ah, al;
        if (t < 8) {
            // Toeplitz: A[m][k] = kr[127 - m + k], k = 16t + 8h + e
            int I0 = 127 - m + 16*t + 8*h;
            unsigned short vh[8], vl[8];
#pragma unroll
            for (int e = 0; e < 8; ++e) { vh[e] = krh[I0 + e]; vl[e] = krl[I0 + e]; }
            ah = pack8(vh); al = pack8(vl);
        } else {
            int nbase = 16*t - 128 + 8*h;
            ah = ld_frag(&Uh[m*UKP + nbase]);
            al = ld_frag(&Ul[m*UKP + nbase]);
        }
#pragma unroll
        for (int nt = 0; nt < 2; ++nt) {
            bf16x8 bh = ld_frag(&Bh[(nt*32 + lane2)*BKP + 16*t + 8*h]);
            bf16x8 bl = ld_frag(&Bl[(nt*32 + lane2)*BKP + 16*t + 8*h]);
            a0[nt] = __builtin_amdgcn_mfma_f32_32x32x16_bf16(ah, bh, a0[nt], 0, 0, 0);
            a1[nt] = __builtin_amdgcn_mfma_f32_32x32x16_bf16(al, bh, a1[nt], 0, 0, 0);
            a2[nt] = __builtin_amdgcn_mfma_f32_32x32x16_bf16(ah, bl, a2[nt], 0, 0, 0);
        }
    }

#pragma unroll
    for (int nt = 0; nt < 2; ++nt) {
        f32x16 s = a0[nt] + a1[nt] + a2[nt];
        int col = g*64 + nt*32 + lane2;
        int j = col >> 3, b = col & 7;
        float* op = out + ((long)(b*NC + c))*LSEQ + j*QC;
#pragma unroll
        for (int r = 0; r < 16; ++r) {
            int row = w*32 + (r & 3) + 8*(r >> 2) + 4*h;
            op[row] = s[r];
        }
    }
}

extern "C" void kernel_launch(void* const* d_in, const int* in_sizes, int n_in,
                              void* d_out, int out_size, void* d_ws, size_t ws_size,
                              hipStream_t stream)
{
    const float* signal = (const float*)d_in[0];
    const float* B      = (const float*)d_in[1];
    const float* C      = (const float*)d_in[2];
    const float* A      = (const float*)d_in[3];
    const float* dt     = (const float*)d_in[4];
    float* ws  = (float*)d_ws;
    float* out = (float*)d_out;

    hipLaunchKernelGGL(prep_cols_kernel,  dim3(48),        dim3(256), 0, stream, A, B, dt, ws);
    hipLaunchKernelGGL(chains_kernel,     dim3(320),       dim3(64),  0, stream, C, ws);
    hipLaunchKernelGGL(fchunk_mfma_kernel,dim3(NC, 4),     dim3(256), 0, stream, signal, ws);
    hipLaunchKernelGGL(scan_kernel,       dim3(NB*NC),     dim3(64),  0, stream, ws);
    hipLaunchKernelGGL(output_mfma_kernel,dim3(NC, 4),     dim3(256), 0, stream, signal, ws, out);
}

// Round 4
// 98.750 us; speedup vs baseline: 5.0339x; 1.2819x over previous
//
#include <hip/hip_runtime.h>

#define N 64
#define NC 128
#define NB 8
#define LSEQ 4096
#define QC 128
#define NCHUNK (LSEQ/QC)   // 32

// workspace layout (float offsets)
#define OFF_ABAR 0                         // [n][m] 64x64  A_bar row-major
#define OFF_AQ   (OFF_ABAR + N*N)          // [n][m] 64x64  A_bar^128
#define OFF_BBAR (OFF_AQ + N*N)            // [n][c] 64x128
#define OFF_K    (OFF_BBAR + N*NC)         // k[c][p]  128x128
#define OFF_W    (OFF_K + NC*QC)           // W[p][c][n] 128x128x64
#define OFF_U    (OFF_W + QC*NC*N)         // U[c][q][n] 128x128x64
#define OFF_FS   (OFF_U + NC*QC*N)         // FS[j][b][c][n] 32x8x128x64
// transient region aliased onto FS (dead before fchunk rewrites all of FS):
#define OFF_ABT  (OFF_FS)                  // [j][l] = A_bar[l][j]
#define OFF_A2   (OFF_FS + 4096)           // A^2 row-major
#define OFF_A2T  (OFF_FS + 2*4096)         // (A^2)^T row-major
#define OFF_A4   (OFF_FS + 3*4096)         // A^4 row-major
#define OFF_A4T  (OFF_FS + 4*4096)         // (A^4)^T row-major

typedef __attribute__((ext_vector_type(8)))  __bf16 bf16x8;
typedef __attribute__((ext_vector_type(16))) float  f32x16;
typedef __attribute__((ext_vector_type(4)))  unsigned int u32x4;

__device__ __forceinline__ float rdlane(float v, int l) {
    return __int_as_float(__builtin_amdgcn_readlane(__float_as_int(v), l));
}

__device__ __forceinline__ void load_row64(const float* __restrict__ p, float (&ar)[64]) {
    const float4* rp = reinterpret_cast<const float4*>(p);
#pragma unroll
    for (int t = 0; t < 16; ++t) {
        float4 v = rp[t];
        ar[4*t+0] = v.x; ar[4*t+1] = v.y; ar[4*t+2] = v.z; ar[4*t+3] = v.w;
    }
}

// y_l = sum_m ar[m] * v_m  (v broadcast via readlane)
__device__ __forceinline__ float matvec64(const float (&ar)[64], float v) {
    float a0 = 0.f, a1 = 0.f, a2 = 0.f, a3 = 0.f;
#pragma unroll
    for (int m = 0; m < 64; m += 4) {
        a0 += ar[m+0] * rdlane(v, m+0);
        a1 += ar[m+1] * rdlane(v, m+1);
        a2 += ar[m+2] * rdlane(v, m+2);
        a3 += ar[m+3] * rdlane(v, m+3);
    }
    return (a0 + a1) + (a2 + a3);
}

// fp32 -> (hi, lo) bf16 pair, RNE both
__device__ __forceinline__ void f2bf_hl(float x, unsigned short& hi, unsigned short& lo) {
    unsigned u = __float_as_uint(x);
    unsigned r = (u + 0x7fffu + ((u >> 16) & 1u)) >> 16;
    hi = (unsigned short)r;
    float fh = __uint_as_float(r << 16);
    float l  = x - fh;
    unsigned ul = __float_as_uint(l);
    unsigned rl = (ul + 0x7fffu + ((ul >> 16) & 1u)) >> 16;
    lo = (unsigned short)rl;
}

__device__ __forceinline__ bf16x8 ld_frag(const unsigned short* p) {
    u32x4 v = *(const u32x4*)p;
    return __builtin_bit_cast(bf16x8, v);
}

__device__ __forceinline__ bf16x8 pack8(const unsigned short* v) {
    u32x4 u;
    u.x = v[0] | ((unsigned)v[1] << 16);
    u.y = v[2] | ((unsigned)v[3] << 16);
    u.z = v[4] | ((unsigned)v[5] << 16);
    u.w = v[6] | ((unsigned)v[7] << 16);
    return __builtin_bit_cast(bf16x8, u);
}

// ---------------------------------------------------------------------------
// prep_cols: forward-substitution column solves of (I - h A) x = v.
// ---------------------------------------------------------------------------
__global__ __launch_bounds__(256) void prep_cols_kernel(const float* __restrict__ A,
    const float* __restrict__ B, const float* __restrict__ dtp,
    float* __restrict__ ws)
{
    __shared__ float AT[64*65];    // AT[i][l] = A[l][i]
    const int tid  = threadIdx.x;
    const int wave = tid >> 6;
    const int l    = tid & 63;
    const float dt = dtp[0];
    const float h  = 0.5f * dt;

    for (int idx = tid; idx < 64*64; idx += 256) {
        int row = idx >> 6, i = idx & 63;
        AT[i*65 + row] = A[idx];
    }
    __syncthreads();

    const float rdv = 1.0f / (1.0f - h * AT[l*65 + l]);
    const int colid = blockIdx.x * 4 + wave;

    float r;
    if (colid < 64) {
        int j = colid;
        r = ((l == j) ? 1.0f : 0.0f) + h * AT[j*65 + l];
    } else {
        int c = colid - 64;
        r = B[l*NC + c];
    }

#pragma unroll
    for (int i = 0; i < 64; ++i) {
        float xi = rdlane(r, i) * rdlane(rdv, i);
        float a  = AT[i*65 + l];
        r = fmaf(h * xi, a, r);
        r = (l == i) ? xi : r;
    }

    if (colid < 64) {
        ws[OFF_ABAR + l*64 + colid] = r;
        ws[OFF_ABT  + colid*64 + l] = r;
    } else {
        ws[OFF_BBAR + l*NC + (colid - 64)] = dt * r;
    }
}

// ---------------------------------------------------------------------------
// pow_sq: dst = src^2 (and transpose). Column j per wave: one matvec.
//   y_l = sum_m src[l][m] * srcT[j][m](broadcast) ; dst[l][j], dstT[j][l].
// ---------------------------------------------------------------------------
__global__ __launch_bounds__(256) void pow_sq_kernel(const float* __restrict__ src,
    const float* __restrict__ srcT, float* __restrict__ dst, float* __restrict__ dstT)
{
    const int tid = threadIdx.x;
    const int wave = tid >> 6;
    const int l = tid & 63;
    const int j = blockIdx.x * 4 + wave;

    float ar[64];
    load_row64(src + l*64, ar);
    float x = srcT[j*64 + l];          // lane m holds src[m][j]
    float y = matvec64(ar, x);
    dst[l*64 + j]  = y;
    dstT[j*64 + l] = y;
}

// ---------------------------------------------------------------------------
// chains: stride-4 chains with A^4 / (A^4)^T. 4 waves per block.
//   blocks   0..127 : W[p][c][:], wave i owns p = i, i+4, ..., i+124
//   blocks 128..255 : U[c][q][:], wave i owns q = i, i+4, ...
//   blocks 256..271 : AQ columns (4 per block), AQ = (A^4)^32
// ---------------------------------------------------------------------------
__global__ __launch_bounds__(256, 1) void chains_kernel(const float* __restrict__ C,
    float* __restrict__ ws)
{
    __shared__ float seed[3][64];
    const int bid = blockIdx.x;
    const int tid = threadIdx.x;
    const int w4  = tid >> 6;
    const int l   = tid & 63;

    if (bid < 128) {                       // ---- W chain, channel c
        const int c = bid;
        float a4[64];
        load_row64(ws + OFF_A4 + l*64, a4);
        float cur;
        if (w4 == 0) {
            float ab[64];
            load_row64(ws + OFF_ABAR + l*64, ab);
            float t = ws[OFF_BBAR + l*NC + c];
            cur = t;
            t = matvec64(ab, t); seed[0][l] = t;
            t = matvec64(ab, t); seed[1][l] = t;
            t = matvec64(ab, t); seed[2][l] = t;
        }
        __syncthreads();
        if (w4 > 0) cur = seed[w4 - 1][l];
        int p = w4;
#pragma unroll 1
        for (int it = 0; it < 32; ++it) {
            ws[OFF_W + (p*NC + c)*N + l] = cur;
            if (it < 31) { cur = matvec64(a4, cur); p += 4; }
        }
    } else if (bid < 256) {                // ---- U chain, channel c
        const int c = bid - 128;
        float a4t[64];
        load_row64(ws + OFF_A4T + l*64, a4t);
        float cur;
        if (w4 == 0) {
            float abt[64];
            load_row64(ws + OFF_ABT + l*64, abt);
            float t = C[l*NC + c];
            t = matvec64(abt, t); cur = t;            // U_0
            t = matvec64(abt, t); seed[0][l] = t;     // U_1
            t = matvec64(abt, t); seed[1][l] = t;     // U_2
            t = matvec64(abt, t); seed[2][l] = t;     // U_3
        }
        __syncthreads();
        if (w4 > 0) cur = seed[w4 - 1][l];
        int q = w4;
#pragma unroll 1
        for (int it = 0; it < 32; ++it) {
            ws[OFF_U + (c*QC + q)*N + l] = cur;
            if (it < 31) { cur = matvec64(a4t, cur); q += 4; }
        }
    } else {                               // ---- AQ columns
        const int j = (bid - 256)*4 + w4;
        float a4[64];
        load_row64(ws + OFF_A4 + l*64, a4);
        float cur = (l == j) ? 1.0f : 0.0f;
#pragma unroll 1
        for (int it = 0; it < 32; ++it) cur = matvec64(a4, cur);
        ws[OFF_AQ + l*64 + j] = cur;
    }
}

// ---------------------------------------------------------------------------
// kdot: k[c][p] = sum_n C[n][c] * W[p][c][n], via LDS transpose. Block = c.
// ---------------------------------------------------------------------------
__global__ __launch_bounds__(256) void kdot_kernel(const float* __restrict__ C,
    float* __restrict__ ws)
{
    __shared__ float Wt[64*129];   // [n][p] padded
    __shared__ float Cs[64];
    const int tid = threadIdx.x;
    const int c = blockIdx.x;

    for (int idx = tid; idx < 128*64; idx += 256) {
        int p = idx >> 6, n = idx & 63;
        Wt[n*129 + p] = ws[OFF_W + (p*NC + c)*N + n];
    }
    if (tid < 64) Cs[tid] = C[tid*NC + c];
    __syncthreads();
    if (tid < 128) {
        const int p = tid;
        float acc = 0.0f;
#pragma unroll
        for (int n = 0; n < 64; ++n) acc += Wt[n*129 + p] * Cs[n];
        ws[OFF_K + c*QC + p] = acc;
    }
}

// ---------------------------------------------------------------------------
// fchunk (MFMA): per channel c, col-group g (64 cols of (j,b)):
//   F[64 n][64 col] = Wrev[64 n][128 kq] @ X[128 kq][64 col], 3-pass bf16 split
// ---------------------------------------------------------------------------
#define FKP 136
__global__ __launch_bounds__(256, 2) void fchunk_mfma_kernel(const float* __restrict__ x,
    float* __restrict__ ws)
{
    __shared__ __align__(16) unsigned short Wh[64*FKP], Wl[64*FKP];
    __shared__ __align__(16) unsigned short Xh[64*FKP], Xl[64*FKP];
    const int tid = threadIdx.x;
    const int c = blockIdx.x;
    const int g = blockIdx.y;

    for (int idx = tid; idx < 128*64; idx += 256) {
        int p = idx >> 6, nn = idx & 63;
        float wv = ws[OFF_W + (p*NC + c)*N + nn];
        unsigned short hi, lo; f2bf_hl(wv, hi, lo);
        int kq = 127 - p;
        Wh[nn*FKP + kq] = hi; Wl[nn*FKP + kq] = lo;
    }
    for (int idx = tid; idx < 64*128; idx += 256) {
        int col = idx >> 7, kk = idx & 127;
        int j = g*8 + (col >> 3), b = col & 7;
        float xv = x[((long)(b*NC + c))*LSEQ + j*QC + kk];
        unsigned short hi, lo; f2bf_hl(xv, hi, lo);
        Xh[col*FKP + kk] = hi; Xl[col*FKP + kk] = lo;
    }
    __syncthreads();

    const int l = tid & 63;
    const int w = tid >> 6;
    const int lane2 = l & 31;
    const int h = l >> 5;
    const int mt = w & 1;
    const int nt = w >> 1;

    f32x16 a0 = {}, a1 = {}, a2 = {};
#pragma unroll
    for (int t = 0; t < 8; ++t) {
        bf16x8 ah = ld_frag(&Wh[(mt*32 + lane2)*FKP + 16*t + 8*h]);
        bf16x8 al = ld_frag(&Wl[(mt*32 + lane2)*FKP + 16*t + 8*h]);
        bf16x8 bh = ld_frag(&Xh[(nt*32 + lane2)*FKP + 16*t + 8*h]);
        bf16x8 bl = ld_frag(&Xl[(nt*32 + lane2)*FKP + 16*t + 8*h]);
        a0 = __builtin_amdgcn_mfma_f32_32x32x16_bf16(ah, bh, a0, 0, 0, 0);
        a1 = __builtin_amdgcn_mfma_f32_32x32x16_bf16(al, bh, a1, 0, 0, 0);
        a2 = __builtin_amdgcn_mfma_f32_32x32x16_bf16(ah, bl, a2, 0, 0, 0);
    }
    f32x16 s = a0 + a1 + a2;
    const int col = g*64 + nt*32 + lane2;
    const int j = col >> 3, b = col & 7;
#pragma unroll
    for (int r = 0; r < 16; ++r) {
        int n = mt*32 + (r & 3) + 8*(r >> 2) + 4*h;
        ws[OFF_FS + ((j*NB + b)*NC + c)*N + n] = s[r];
    }
}

// ---------------------------------------------------------------------------
// scan: per (b,c): S_{j+1} = AQ S_j + F_j over 32 chunks, in-place.
// ---------------------------------------------------------------------------
__global__ __launch_bounds__(64) void scan_kernel(float* __restrict__ ws)
{
    const int l = threadIdx.x;
    const int b = blockIdx.x >> 7;
    const int c = blockIdx.x & 127;

    float aq[64];
    load_row64(ws + OFF_AQ + l*64, aq);
    float s = ws[OFF_FS + ((0*NB + b)*NC + c)*N + l];
    for (int j = 1; j <= NCHUNK - 2; ++j) {
        float f = ws[OFF_FS + ((j*NB + b)*NC + c)*N + l];
        float a0 = f, a1 = 0.f, a2 = 0.f, a3 = 0.f;
#pragma unroll
        for (int m = 0; m < 64; m += 4) {
            a0 += aq[m+0] * rdlane(s, m+0);
            a1 += aq[m+1] * rdlane(s, m+1);
            a2 += aq[m+2] * rdlane(s, m+2);
            a3 += aq[m+3] * rdlane(s, m+3);
        }
        s = (a0 + a1) + (a2 + a3);
        ws[OFF_FS + ((j*NB + b)*NC + c)*N + l] = s;
    }
}

// ---------------------------------------------------------------------------
// output (MFMA): per channel c, col-group g: Y[128 q][64 col] =
//   [T | U](128 x 192) @ [X ; S](192 x 64), 3-pass bf16 split.
// ---------------------------------------------------------------------------
#define BKP 200
#define UKP 72
__global__ __launch_bounds__(256, 1) void output_mfma_kernel(const float* __restrict__ x,
    const float* __restrict__ ws, float* __restrict__ out)
{
    __shared__ __align__(16) unsigned short krh[256], krl[256];
    __shared__ __align__(16) unsigned short Uh[128*UKP], Ul[128*UKP];
    __shared__ __align__(16) unsigned short Bh[64*BKP], Bl[64*BKP];
    const int tid = threadIdx.x;
    const int c = blockIdx.x;
    const int g = blockIdx.y;

    {
        int I = tid;
        if (I < 256) {
            float kv = (I < 128) ? ws[OFF_K + c*QC + (127 - I)] : 0.0f;
            unsigned short hi, lo; f2bf_hl(kv, hi, lo);
            krh[I] = hi; krl[I] = lo;
        }
    }
    for (int idx = tid; idx < 128*64; idx += 256) {
        int qq = idx >> 6, nn = idx & 63;
        float uv = ws[OFF_U + (c*QC + qq)*N + nn];
        unsigned short hi, lo; f2bf_hl(uv, hi, lo);
        Uh[qq*UKP + nn] = hi; Ul[qq*UKP + nn] = lo;
    }
    for (int idx = tid; idx < 64*128; idx += 256) {
        int col = idx >> 7, kk = idx & 127;
        int j = g*8 + (col >> 3), b = col & 7;
        float xv = x[((long)(b*NC + c))*LSEQ + j*QC + kk];
        unsigned short hi, lo; f2bf_hl(xv, hi, lo);
        Bh[col*BKP + kk] = hi; Bl[col*BKP + kk] = lo;
    }
    for (int idx = tid; idx < 64*64; idx += 256) {
        int col = idx >> 6, nn = idx & 63;
        int j = g*8 + (col >> 3), b = col & 7;
        float sv = (j > 0) ? ws[OFF_FS + (((j-1)*NB + b)*NC + c)*N + nn] : 0.0f;
        unsigned short hi, lo; f2bf_hl(sv, hi, lo);
        Bh[col*BKP + 128 + nn] = hi; Bl[col*BKP + 128 + nn] = lo;
    }
    __syncthreads();

    const int l = tid & 63;
    const int w = tid >> 6;
    const int lane2 = l & 31;
    const int h = l >> 5;
    const int m = w*32 + lane2;

    f32x16 a0[2] = {{}, {}}, a1[2] = {{}, {}}, a2[2] = {{}, {}};

#pragma unroll
    for (int t = 0; t < 12; ++t) {
        bf16x8 ah, al;
        if (t < 8) {
            int I0 = 127 - m + 16*t + 8*h;
            unsigned short vh[8], vl[8];
#pragma unroll
            for (int e = 0; e < 8; ++e) { vh[e] = krh[I0 + e]; vl[e] = krl[I0 + e]; }
            ah = pack8(vh); al = pack8(vl);
        } else {
            int nbase = 16*t - 128 + 8*h;
            ah = ld_frag(&Uh[m*UKP + nbase]);
            al = ld_frag(&Ul[m*UKP + nbase]);
        }
#pragma unroll
        for (int nt = 0; nt < 2; ++nt) {
            bf16x8 bh = ld_frag(&Bh[(nt*32 + lane2)*BKP + 16*t + 8*h]);
            bf16x8 bl = ld_frag(&Bl[(nt*32 + lane2)*BKP + 16*t + 8*h]);
            a0[nt] = __builtin_amdgcn_mfma_f32_32x32x16_bf16(ah, bh, a0[nt], 0, 0, 0);
            a1[nt] = __builtin_amdgcn_mfma_f32_32x32x16_bf16(al, bh, a1[nt], 0, 0, 0);
            a2[nt] = __builtin_amdgcn_mfma_f32_32x32x16_bf16(ah, bl, a2[nt], 0, 0, 0);
        }
    }

#pragma unroll
    for (int nt = 0; nt < 2; ++nt) {
        f32x16 s = a0[nt] + a1[nt] + a2[nt];
        int col = g*64 + nt*32 + lane2;
        int j = col >> 3, b = col & 7;
        float* op = out + ((long)(b*NC + c))*LSEQ + j*QC;
#pragma unroll
        for (int r = 0; r < 16; ++r) {
            int row = w*32 + (r & 3) + 8*(r >> 2) + 4*h;
            op[row] = s[r];
        }
    }
}

extern "C" void kernel_launch(void* const* d_in, const int* in_sizes, int n_in,
                              void* d_out, int out_size, void* d_ws, size_t ws_size,
                              hipStream_t stream)
{
    const float* signal = (const float*)d_in[0];
    const float* B      = (const float*)d_in[1];
    const float* C      = (const float*)d_in[2];
    const float* A      = (const float*)d_in[3];
    const float* dt     = (const float*)d_in[4];
    float* ws  = (float*)d_ws;
    float* out = (float*)d_out;

    hipLaunchKernelGGL(prep_cols_kernel,  dim3(48),     dim3(256), 0, stream, A, B, dt, ws);
    hipLaunchKernelGGL(pow_sq_kernel,     dim3(16),     dim3(256), 0, stream,
                       ws + OFF_ABAR, ws + OFF_ABT, ws + OFF_A2, ws + OFF_A2T);
    hipLaunchKernelGGL(pow_sq_kernel,     dim3(16),     dim3(256), 0, stream,
                       ws + OFF_A2, ws + OFF_A2T, ws + OFF_A4, ws + OFF_A4T);
    hipLaunchKernelGGL(chains_kernel,     dim3(272),    dim3(256), 0, stream, C, ws);
    hipLaunchKernelGGL(kdot_kernel,       dim3(NC),     dim3(256), 0, stream, C, ws);
    hipLaunchKernelGGL(fchunk_mfma_kernel,dim3(NC, 4),  dim3(256), 0, stream, signal, ws);
    hipLaunchKernelGGL(scan_kernel,       dim3(NB*NC),  dim3(64),  0, stream, ws);
    hipLaunchKernelGGL(output_mfma_kernel,dim3(NC, 4),  dim3(256), 0, stream, signal, ws, out);
}

// Round 5
// 83.016 us; speedup vs baseline: 5.9880x; 1.1895x over previous
//
#include <hip/hip_runtime.h>

#define N 64
#define NC 128
#define NB 8
#define LSEQ 4096
#define QC 128
#define NCHUNK 32

// fp32 regions (float offsets into ws)
#define OFF_ABAR 0
#define OFF_AQ   4096
#define OFF_BBAR 8192          // [n][c] 64x128
#define OFF_ABT  16384
#define OFF_A2   20480
#define OFF_A2T  24576
#define OFF_A4   28672
#define OFF_A4T  32768
#define OFF_FS   36864         // [j][b][c][n] 32x8x128x64 fp32 (F values from fchunk)
#define U16_BASE (OFF_FS + NCHUNK*NB*NC*N)   // u16 planes start here (16B aligned)

// u16 offsets (in u16 units) relative to u16b = (unsigned short*)(ws + U16_BASE)
#define OFF_WH 0                       // [c][n][kq] 128x64x128, kq = 127-p
#define OFF_WL (OFF_WH + NC*N*QC)
#define OFF_UH (OFF_WL + NC*N*QC)      // [c][q][n]
#define OFF_UL (OFF_UH + NC*QC*N)
#define OFF_KH (OFF_UL + NC*QC*N)      // [c][256] reversed-extended k
#define OFF_KL (OFF_KH + NC*256)
#define OFF_SH (OFF_KL + NC*256)       // [slot][b][c][n], slot j holds S_j (slot0 = 0)
#define OFF_SL (OFF_SH + NCHUNK*NB*NC*N)

typedef __attribute__((ext_vector_type(8)))  __bf16 bf16x8;
typedef __attribute__((ext_vector_type(16))) float  f32x16;
typedef __attribute__((ext_vector_type(4)))  unsigned int u32x4;

__device__ __forceinline__ float rdlane(float v, int l) {
    return __int_as_float(__builtin_amdgcn_readlane(__float_as_int(v), l));
}

__device__ __forceinline__ void load_row64(const float* __restrict__ p, float (&ar)[64]) {
    const float4* rp = reinterpret_cast<const float4*>(p);
#pragma unroll
    for (int t = 0; t < 16; ++t) {
        float4 v = rp[t];
        ar[4*t+0] = v.x; ar[4*t+1] = v.y; ar[4*t+2] = v.z; ar[4*t+3] = v.w;
    }
}

__device__ __forceinline__ float matvec64(const float (&ar)[64], float v) {
    float a0 = 0.f, a1 = 0.f, a2 = 0.f, a3 = 0.f;
#pragma unroll
    for (int m = 0; m < 64; m += 4) {
        a0 += ar[m+0] * rdlane(v, m+0);
        a1 += ar[m+1] * rdlane(v, m+1);
        a2 += ar[m+2] * rdlane(v, m+2);
        a3 += ar[m+3] * rdlane(v, m+3);
    }
    return (a0 + a1) + (a2 + a3);
}

// fp32 -> (hi, lo) bf16 pair, RNE both
__device__ __forceinline__ void f2bf_hl(float x, unsigned short& hi, unsigned short& lo) {
    unsigned u = __float_as_uint(x);
    unsigned r = (u + 0x7fffu + ((u >> 16) & 1u)) >> 16;
    hi = (unsigned short)r;
    float fh = __uint_as_float(r << 16);
    float l  = x - fh;
    unsigned ul = __float_as_uint(l);
    unsigned rl = (ul + 0x7fffu + ((ul >> 16) & 1u)) >> 16;
    lo = (unsigned short)rl;
}

// pack two fp32 -> hi-plane u32 (returned) and lo-plane u32 (out-param)
__device__ __forceinline__ unsigned pack_hl2(float x0, float x1, unsigned& lo32) {
    unsigned short h0, l0, h1, l1;
    f2bf_hl(x0, h0, l0); f2bf_hl(x1, h1, l1);
    lo32 = (unsigned)l0 | ((unsigned)l1 << 16);
    return (unsigned)h0 | ((unsigned)h1 << 16);
}

__device__ __forceinline__ bf16x8 ld_frag(const unsigned short* p) {
    u32x4 v = *(const u32x4*)p;     // 16B-aligned by construction
    return __builtin_bit_cast(bf16x8, v);
}

__device__ __forceinline__ bf16x8 pack8(const unsigned short* v) {
    u32x4 u;
    u.x = v[0] | ((unsigned)v[1] << 16);
    u.y = v[2] | ((unsigned)v[3] << 16);
    u.z = v[4] | ((unsigned)v[5] << 16);
    u.w = v[6] | ((unsigned)v[7] << 16);
    return __builtin_bit_cast(bf16x8, u);
}

// ---------------------------------------------------------------------------
// prep_cols: forward-substitution column solves of (I - h A) x = v.
// ---------------------------------------------------------------------------
__global__ __launch_bounds__(256) void prep_cols_kernel(const float* __restrict__ A,
    const float* __restrict__ B, const float* __restrict__ dtp,
    float* __restrict__ ws)
{
    __shared__ float AT[64*65];    // AT[i][l] = A[l][i]
    const int tid  = threadIdx.x;
    const int wave = tid >> 6;
    const int l    = tid & 63;
    const float dt = dtp[0];
    const float h  = 0.5f * dt;

    for (int idx = tid; idx < 64*64; idx += 256) {
        int row = idx >> 6, i = idx & 63;
        AT[i*65 + row] = A[idx];
    }
    __syncthreads();

    const float rdv = 1.0f / (1.0f - h * AT[l*65 + l]);
    const int colid = blockIdx.x * 4 + wave;

    float r;
    if (colid < 64) {
        int j = colid;
        r = ((l == j) ? 1.0f : 0.0f) + h * AT[j*65 + l];
    } else {
        int c = colid - 64;
        r = B[l*NC + c];
    }

#pragma unroll
    for (int i = 0; i < 64; ++i) {
        float xi = rdlane(r, i) * rdlane(rdv, i);
        float a  = AT[i*65 + l];
        r = fmaf(h * xi, a, r);
        r = (l == i) ? xi : r;
    }

    if (colid < 64) {
        ws[OFF_ABAR + l*64 + colid] = r;
        ws[OFF_ABT  + colid*64 + l] = r;
    } else {
        ws[OFF_BBAR + l*NC + (colid - 64)] = dt * r;
    }
}

// ---------------------------------------------------------------------------
// pow_sq: dst = src^2 (and transpose). Column j per wave: one matvec.
// ---------------------------------------------------------------------------
__global__ __launch_bounds__(256) void pow_sq_kernel(const float* __restrict__ src,
    const float* __restrict__ srcT, float* __restrict__ dst, float* __restrict__ dstT)
{
    const int tid = threadIdx.x;
    const int wave = tid >> 6;
    const int l = tid & 63;
    const int j = blockIdx.x * 4 + wave;

    float ar[64];
    load_row64(src + l*64, ar);
    float x = srcT[j*64 + l];
    float y = matvec64(ar, x);
    dst[l*64 + j]  = y;
    dstT[j*64 + l] = y;
}

// ---------------------------------------------------------------------------
// chains: stride-4 chains with A^4 / (A^4)^T. 4 waves per block.
//   blocks   0..127 : W chain for channel c -> WH/WL (bf16, [n][kq] reversed)
//                     + inline k-dot -> KH/KL (reversed-extended, bf16)
//   blocks 128..255 : U chain for channel c -> UH/UL (bf16, [q][n])
//   blocks 256..271 : AQ columns (fp32, for scan)
// ---------------------------------------------------------------------------
__global__ __launch_bounds__(256, 1) void chains_kernel(const float* __restrict__ C,
    float* __restrict__ ws)
{
    __shared__ float Wlds[128][65];
    __shared__ float karr[128];
    __shared__ float seed[3][64];
    unsigned short* u16b = (unsigned short*)(ws + U16_BASE);
    const int bid = blockIdx.x;
    const int tid = threadIdx.x;
    const int w4  = tid >> 6;
    const int l   = tid & 63;

    if (bid < 128) {                       // ---- W chain + k, channel c
        const int c = bid;
        float a4[64];
        load_row64(ws + OFF_A4 + l*64, a4);
        const float Cl = C[l*NC + c];
        float cur;
        if (w4 == 0) {
            float ab[64];
            load_row64(ws + OFF_ABAR + l*64, ab);
            float t = ws[OFF_BBAR + l*NC + c];
            cur = t;
            t = matvec64(ab, t); seed[0][l] = t;
            t = matvec64(ab, t); seed[1][l] = t;
            t = matvec64(ab, t); seed[2][l] = t;
        }
        __syncthreads();
        if (w4 > 0) cur = seed[w4 - 1][l];
        int p = w4;
#pragma unroll 1
        for (int it = 0; it < 32; ++it) {
            Wlds[p][l] = cur;
            float d = Cl * cur;                      // off-critical-path k-dot
            d += __shfl_xor(d, 32, 64); d += __shfl_xor(d, 16, 64);
            d += __shfl_xor(d, 8, 64);  d += __shfl_xor(d, 4, 64);
            d += __shfl_xor(d, 2, 64);  d += __shfl_xor(d, 1, 64);
            if (l == 0) karr[p] = d;
            if (it < 31) { cur = matvec64(a4, cur); p += 4; }
        }
        __syncthreads();
        // WH/WL[c][n][kq], kq = 127-p, packed u32 writes (coalesced)
        for (int idx = tid; idx < 64*64; idx += 256) {
            int n = idx >> 6, i2 = idx & 63;
            int kq = i2*2;
            float w0 = Wlds[127 - kq][n];
            float w1 = Wlds[126 - kq][n];
            unsigned lo32, hi32 = pack_hl2(w0, w1, lo32);
            ((unsigned*)(u16b + OFF_WH + (c*64 + n)*128))[i2] = hi32;
            ((unsigned*)(u16b + OFF_WL + (c*64 + n)*128))[i2] = lo32;
        }
        // KH/KL[c][I]: I<128 -> k[127-I], else 0
        if (tid < 128) {
            int i = tid;                 // u32 index = entries (2i, 2i+1)
            float k0 = (2*i   < 128) ? karr[127 - 2*i] : 0.0f;
            float k1 = (2*i+1 < 128) ? karr[126 - 2*i] : 0.0f;
            unsigned lo32, hi32 = pack_hl2(k0, k1, lo32);
            ((unsigned*)(u16b + OFF_KH + c*256))[i] = hi32;
            ((unsigned*)(u16b + OFF_KL + c*256))[i] = lo32;
        }
    } else if (bid < 256) {                // ---- U chain, channel c
        const int c = bid - 128;
        float a4t[64];
        load_row64(ws + OFF_A4T + l*64, a4t);
        float cur;
        if (w4 == 0) {
            float abt[64];
            load_row64(ws + OFF_ABT + l*64, abt);
            float t = C[l*NC + c];
            t = matvec64(abt, t); cur = t;            // U_0
            t = matvec64(abt, t); seed[0][l] = t;     // U_1
            t = matvec64(abt, t); seed[1][l] = t;     // U_2
            t = matvec64(abt, t); seed[2][l] = t;     // U_3
        }
        __syncthreads();
        if (w4 > 0) cur = seed[w4 - 1][l];
        int q = w4;
#pragma unroll 1
        for (int it = 0; it < 32; ++it) {
            unsigned short hi, lo; f2bf_hl(cur, hi, lo);
            u16b[OFF_UH + (c*QC + q)*64 + l] = hi;
            u16b[OFF_UL + (c*QC + q)*64 + l] = lo;
            if (it < 31) { cur = matvec64(a4t, cur); q += 4; }
        }
    } else {                               // ---- AQ columns (fp32)
        const int j = (bid - 256)*4 + w4;
        float a4[64];
        load_row64(ws + OFF_A4 + l*64, a4);
        float cur = (l == j) ? 1.0f : 0.0f;
#pragma unroll 1
        for (int it = 0; it < 32; ++it) cur = matvec64(a4, cur);
        ws[OFF_AQ + l*64 + j] = cur;
    }
}

// ---------------------------------------------------------------------------
// fchunk (MFMA): per (c, g): F[64 n][64 col] = Wrev @ X, 3-pass bf16 split.
// A-frags direct from global WH/WL; X staged in LDS (vectorized convert).
// ---------------------------------------------------------------------------
__global__ __launch_bounds__(256, 2) void fchunk_mfma_kernel(const float* __restrict__ x,
    float* __restrict__ ws)
{
    __shared__ __align__(16) unsigned Xh32[64*68], Xl32[64*68];   // row stride 136 u16
    const unsigned short* u16b = (const unsigned short*)(ws + U16_BASE);
    const int tid = threadIdx.x;
    const int c = blockIdx.x;
    const int g = blockIdx.y;

    for (int idx = tid; idx < 64*64; idx += 256) {
        int col = idx >> 6, i2 = idx & 63;
        int j = g*8 + (col >> 3), b = col & 7;
        const float2 xv = *reinterpret_cast<const float2*>(
            x + ((long)(b*NC + c))*LSEQ + j*QC + i2*2);
        unsigned lo32, hi32 = pack_hl2(xv.x, xv.y, lo32);
        Xh32[col*68 + i2] = hi32;
        Xl32[col*68 + i2] = lo32;
    }
    __syncthreads();

    const int l = tid & 63;
    const int w = tid >> 6;
    const int lane2 = l & 31;
    const int h = l >> 5;
    const int mt = w & 1;
    const int nt = w >> 1;

    const unsigned short* Xh = (const unsigned short*)Xh32;
    const unsigned short* Xl = (const unsigned short*)Xl32;
    const unsigned short* WHp = u16b + OFF_WH + (c*64 + mt*32 + lane2)*128 + 8*h;
    const unsigned short* WLp = u16b + OFF_WL + (c*64 + mt*32 + lane2)*128 + 8*h;

    f32x16 a0 = {}, a1 = {}, a2 = {};
#pragma unroll
    for (int t = 0; t < 8; ++t) {
        bf16x8 ah = ld_frag(WHp + 16*t);
        bf16x8 al = ld_frag(WLp + 16*t);
        bf16x8 bh = ld_frag(&Xh[(nt*32 + lane2)*136 + 16*t + 8*h]);
        bf16x8 bl = ld_frag(&Xl[(nt*32 + lane2)*136 + 16*t + 8*h]);
        a0 = __builtin_amdgcn_mfma_f32_32x32x16_bf16(ah, bh, a0, 0, 0, 0);
        a1 = __builtin_amdgcn_mfma_f32_32x32x16_bf16(al, bh, a1, 0, 0, 0);
        a2 = __builtin_amdgcn_mfma_f32_32x32x16_bf16(ah, bl, a2, 0, 0, 0);
    }
    f32x16 s = a0 + a1 + a2;
    const int col = g*64 + nt*32 + lane2;
    const int j = col >> 3, b = col & 7;
#pragma unroll
    for (int r = 0; r < 16; ++r) {
        int n = mt*32 + (r & 3) + 8*(r >> 2) + 4*h;
        ws[OFF_FS + ((j*NB + b)*NC + c)*N + n] = s[r];
    }
}

// ---------------------------------------------------------------------------
// scan: per (b,c): S_{j+1} = AQ S_j + F_j; writes bf16 SH/SL slots (slot j = S_j).
// ---------------------------------------------------------------------------
__global__ __launch_bounds__(64) void scan_kernel(float* __restrict__ ws)
{
    unsigned short* u16b = (unsigned short*)(ws + U16_BASE);
    const int l = threadIdx.x;
    const int b = blockIdx.x >> 7;
    const int c = blockIdx.x & 127;

    float aq[64];
    load_row64(ws + OFF_AQ + l*64, aq);

    u16b[OFF_SH + ((0*NB + b)*NC + c)*64 + l] = 0;   // S_0 = 0
    u16b[OFF_SL + ((0*NB + b)*NC + c)*64 + l] = 0;

    float s = ws[OFF_FS + ((0*NB + b)*NC + c)*N + l];  // S_1
    {
        unsigned short hi, lo; f2bf_hl(s, hi, lo);
        u16b[OFF_SH + ((1*NB + b)*NC + c)*64 + l] = hi;
        u16b[OFF_SL + ((1*NB + b)*NC + c)*64 + l] = lo;
    }
    for (int j = 1; j <= NCHUNK - 2; ++j) {
        float f = ws[OFF_FS + ((j*NB + b)*NC + c)*N + l];
        float a0 = f, a1 = 0.f, a2 = 0.f, a3 = 0.f;
#pragma unroll
        for (int m = 0; m < 64; m += 4) {
            a0 += aq[m+0] * rdlane(s, m+0);
            a1 += aq[m+1] * rdlane(s, m+1);
            a2 += aq[m+2] * rdlane(s, m+2);
            a3 += aq[m+3] * rdlane(s, m+3);
        }
        s = (a0 + a1) + (a2 + a3);
        unsigned short hi, lo; f2bf_hl(s, hi, lo);
        u16b[OFF_SH + (((j+1)*NB + b)*NC + c)*64 + l] = hi;
        u16b[OFF_SL + (((j+1)*NB + b)*NC + c)*64 + l] = lo;
    }
}

// ---------------------------------------------------------------------------
// output (MFMA): per (c, g): Y[128 q][64 col] = [T|U] @ [X;S], 3-pass bf16.
// T gathered from LDS kr; U-frags and S-frags direct from global bf16 planes.
// ---------------------------------------------------------------------------
__global__ __launch_bounds__(256, 2) void output_mfma_kernel(const float* __restrict__ x,
    const float* __restrict__ ws, float* __restrict__ out)
{
    __shared__ __align__(16) unsigned krh32[128], krl32[128];
    __shared__ __align__(16) unsigned Xh32[64*68], Xl32[64*68];
    const unsigned short* u16b = (const unsigned short*)(ws + U16_BASE);
    const int tid = threadIdx.x;
    const int c = blockIdx.x;
    const int g = blockIdx.y;

    if (tid < 128) {
        krh32[tid] = ((const unsigned*)(u16b + OFF_KH + c*256))[tid];
        krl32[tid] = ((const unsigned*)(u16b + OFF_KL + c*256))[tid];
    }
    for (int idx = tid; idx < 64*64; idx += 256) {
        int col = idx >> 6, i2 = idx & 63;
        int j = g*8 + (col >> 3), b = col & 7;
        const float2 xv = *reinterpret_cast<const float2*>(
            x + ((long)(b*NC + c))*LSEQ + j*QC + i2*2);
        unsigned lo32, hi32 = pack_hl2(xv.x, xv.y, lo32);
        Xh32[col*68 + i2] = hi32;
        Xl32[col*68 + i2] = lo32;
    }
    __syncthreads();

    const int l = tid & 63;
    const int w = tid >> 6;        // m-tile
    const int lane2 = l & 31;
    const int h = l >> 5;
    const int m = w*32 + lane2;    // output row q

    const unsigned short* krh = (const unsigned short*)krh32;
    const unsigned short* krl = (const unsigned short*)krl32;
    const unsigned short* Xh = (const unsigned short*)Xh32;
    const unsigned short* Xl = (const unsigned short*)Xl32;

    f32x16 a0[2] = {{}, {}}, a1[2] = {{}, {}}, a2[2] = {{}, {}};

#pragma unroll
    for (int t = 0; t < 12; ++t) {
        bf16x8 ah, al;
        if (t < 8) {
            int I0 = 127 - m + 16*t + 8*h;
            unsigned short vh[8], vl[8];
#pragma unroll
            for (int e = 0; e < 8; ++e) { vh[e] = krh[I0 + e]; vl[e] = krl[I0 + e]; }
            ah = pack8(vh); al = pack8(vl);
        } else {
            const unsigned short* up = u16b + (c*QC + m)*64 + 16*(t-8) + 8*h;
            ah = ld_frag(up + OFF_UH);
            al = ld_frag(up + OFF_UL);
        }
#pragma unroll
        for (int nt = 0; nt < 2; ++nt) {
            bf16x8 bh, bl;
            if (t < 8) {
                bh = ld_frag(&Xh[(nt*32 + lane2)*136 + 16*t + 8*h]);
                bl = ld_frag(&Xl[(nt*32 + lane2)*136 + 16*t + 8*h]);
            } else {
                int col = g*64 + nt*32 + lane2;
                int j = col >> 3, b = col & 7;
                const unsigned short* sp = u16b + ((j*NB + b)*NC + c)*64 + 16*(t-8) + 8*h;
                bh = ld_frag(sp + OFF_SH);
                bl = ld_frag(sp + OFF_SL);
            }
            a0[nt] = __builtin_amdgcn_mfma_f32_32x32x16_bf16(ah, bh, a0[nt], 0, 0, 0);
            a1[nt] = __builtin_amdgcn_mfma_f32_32x32x16_bf16(al, bh, a1[nt], 0, 0, 0);
            a2[nt] = __builtin_amdgcn_mfma_f32_32x32x16_bf16(ah, bl, a2[nt], 0, 0, 0);
        }
    }

#pragma unroll
    for (int nt = 0; nt < 2; ++nt) {
        f32x16 s = a0[nt] + a1[nt] + a2[nt];
        int col = g*64 + nt*32 + lane2;
        int j = col >> 3, b = col & 7;
        float* op = out + ((long)(b*NC + c))*LSEQ + j*QC;
#pragma unroll
        for (int r = 0; r < 16; ++r) {
            int row = w*32 + (r & 3) + 8*(r >> 2) + 4*h;
            op[row] = s[r];
        }
    }
}

extern "C" void kernel_launch(void* const* d_in, const int* in_sizes, int n_in,
                              void* d_out, int out_size, void* d_ws, size_t ws_size,
                              hipStream_t stream)
{
    const float* signal = (const float*)d_in[0];
    const float* B      = (const float*)d_in[1];
    const float* C      = (const float*)d_in[2];
    const float* A      = (const float*)d_in[3];
    const float* dt     = (const float*)d_in[4];
    float* ws  = (float*)d_ws;
    float* out = (float*)d_out;

    hipLaunchKernelGGL(prep_cols_kernel,  dim3(48),     dim3(256), 0, stream, A, B, dt, ws);
    hipLaunchKernelGGL(pow_sq_kernel,     dim3(16),     dim3(256), 0, stream,
                       ws + OFF_ABAR, ws + OFF_ABT, ws + OFF_A2, ws + OFF_A2T);
    hipLaunchKernelGGL(pow_sq_kernel,     dim3(16),     dim3(256), 0, stream,
                       ws + OFF_A2, ws + OFF_A2T, ws + OFF_A4, ws + OFF_A4T);
    hipLaunchKernelGGL(chains_kernel,     dim3(272),    dim3(256), 0, stream, C, ws);
    hipLaunchKernelGGL(fchunk_mfma_kernel,dim3(NC, 4),  dim3(256), 0, stream, signal, ws);
    hipLaunchKernelGGL(scan_kernel,       dim3(NB*NC),  dim3(64),  0, stream, ws);
    hipLaunchKernelGGL(output_mfma_kernel,dim3(NC, 4),  dim3(256), 0, stream, signal, ws, out);
}